// Round 7
// baseline (389.641 us; speedup 1.0000x reference)
//
#include <hip/hip_runtime.h>
#include <hip/hip_bf16.h>
#include <stdint.h>

#define B_ 4
#define T_ 512
#define H_ 32
#define N_ 64
#define D_ 2048
#define M_ (B_*T_)

typedef __attribute__((ext_vector_type(4))) float f32x4;
typedef __attribute__((ext_vector_type(8))) short short8;

// DPP butterfly add across 16-lane groups: pure VALU.
template <int CTRL>
__device__ __forceinline__ float dpp_add(float x) {
    int t = __builtin_amdgcn_mov_dpp(__float_as_int(x), CTRL, 0xF, 0xF, true);
    return x + __int_as_float(t);
}
__device__ __forceinline__ float bfly16(float x) {
    x = dpp_add<0xB1>(x);    // xor1
    x = dpp_add<0x4E>(x);    // xor2
    x = dpp_add<0x141>(x);   // xor4 row_half_mirror
    x = dpp_add<0x140>(x);   // xor8 row_mirror
    return x;
}

__device__ __forceinline__ void gld4(const float* g, float* l) {
    __builtin_amdgcn_global_load_lds(
        (const __attribute__((address_space(1))) unsigned int*)g,
        (__attribute__((address_space(3))) unsigned int*)l, 4, 0, 0);
}

// ---------------------------------------------------------------------------
// Kernel 1: FUSED WKV-7 scan (prep deleted). R7 accounting: prep's 184 MB
// round-trip (~40-45us) was pure overhead; the scan's step wall (567-640
// cyc/step) has been invariant under 5 scheduling experiments, so we stop
// paying for a separate precompute pass. The producer wave DMAs the RAW
// input rows (r,w,k,v,iclr: 5 x 256B per step, width-4 DMAs since rows are
// only 256B contiguous); every consumer wave derives decay/kk/bb in-register
// (fast exp2/rcp/rsq + bfly16 for sum k^2; ~55 extra VALU/step/wave,
// absorbable under the wall). R4 evidence says numerics tolerance is loose
// (bf16-quantizing these streams left absmax bit-identical).
// Ring: 2 superslots x 4 steps x 5 streams x 64 f32 = 10 KB.
// wave0 vmcnt ledger: 20 DMAs/group + 4 y-stores/group. Top of group g
// (steady): queue = [20 DMA g][4 st g-1][20 DMA g+1] -> vmcnt(24) retires
// data-g. g==0: [20 s0][20 s1] -> vmcnt(20). Refill of slot g&1 (data g+2)
// issued after barrier2 (all waves done reading the slot).
// Blocks >= 256: int32 -> bf16 weight dequant riding in the scan's shadow.
// ---------------------------------------------------------------------------
__global__ __launch_bounds__(512) void wkv_scan(
    const float* __restrict__ r, const float* __restrict__ w,
    const float* __restrict__ k, const float* __restrict__ v,
    const float* __restrict__ iclr, __hip_bfloat16* __restrict__ y,
    const int* __restrict__ q, __hip_bfloat16* __restrict__ o) {
    if (blockIdx.x >= 256) {       // ---- weight dequant part ----
        int i = ((blockIdx.x - 256) * 512 + (int)threadIdx.x) * 4;
        int4 qi = *(const int4*)(q + i);
        __hip_bfloat16 t[4];
        t[0] = __float2bfloat16((float)qi.x);
        t[1] = __float2bfloat16((float)qi.y);
        t[2] = __float2bfloat16((float)qi.z);
        t[3] = __float2bfloat16((float)qi.w);
        *(uint2*)(o + i) = *(uint2*)t;
        return;
    }
    const int bh   = blockIdx.x & 127;
    const int half = blockIdx.x >> 7;
    const int tid  = threadIdx.x;
    const int wave = tid >> 6;
    const int lane = tid & 63;
    const int b = bh >> 5, h = bh & 31;
    const int jg = lane & 15;
    const int rl = lane >> 4;
    const int row = (half * 8 + wave) * 4 + rl;

    __shared__ __align__(16) float ring[2 * 1280];   // 10 KB

    const float L2E = 1.4426950408889634f;

    // prologue: producer fills both superslots (40 DMAs outstanding)
    if (wave == 0) {
#pragma unroll
        for (int gg = 0; gg < 2; ++gg)
#pragma unroll
            for (int i = 0; i < 4; ++i) {
                size_t base = ((size_t)(b * T_ + gg * 4 + i) * H_ + h) * 64 + lane;
                float* l = &ring[gg * 1280 + i * 320];
                gld4(r + base, l);
                gld4(w + base, l + 64);
                gld4(k + base, l + 128);
                gld4(v + base, l + 192);
                gld4(iclr + base, l + 256);
            }
    }

    float S[4] = {0.f, 0.f, 0.f, 0.f};

    for (int g = 0; g < T_ / 4; ++g) {
        if (wave == 0) {
            if (g == 0) { asm volatile("s_waitcnt vmcnt(20)" ::: "memory"); }
            else        { asm volatile("s_waitcnt vmcnt(24)" ::: "memory"); }
        }
        asm volatile("s_barrier" ::: "memory");   // slot g&1 holds data g
        const float* rb0 = &ring[(g & 1) * 1280];

#pragma unroll
        for (int i = 0; i < 4; ++i) {
            const int t = g * 4 + i;
            const float* rb = rb0 + i * 320;

            f32x4 Rc = *(const f32x4*)(rb + jg * 4);
            f32x4 Wc = *(const f32x4*)(rb + 64 + jg * 4);
            f32x4 Kc = *(const f32x4*)(rb + 128 + jg * 4);
            float vcv =                 rb[192 + row];
            f32x4 Ic = *(const f32x4*)(rb + 256 + jg * 4);

            // ---- derive decay / kk / bb in-register ----
            float ss = Kc[0] * Kc[0];
            ss = fmaf(Kc[1], Kc[1], ss);
            ss = fmaf(Kc[2], Kc[2], ss);
            ss = fmaf(Kc[3], Kc[3], ss);
            ss = bfly16(ss);                       // full 64-chan sum
            float rs = __builtin_amdgcn_rsqf(ss + 1e-12f);
            f32x4 Dc, Ac, Bc;
#pragma unroll
            for (int j = 0; j < 4; ++j) {
                float e1 = __builtin_amdgcn_exp2f(Wc[j] * L2E);
                Dc[j] = __builtin_amdgcn_exp2f(-e1 * L2E);      // exp(-exp(w))
                float kkv = Kc[j] * rs;
                Ac[j] = kkv;
                float sg = __builtin_amdgcn_rcpf(
                    1.f + __builtin_amdgcn_exp2f(-Ic[j] * L2E)); // sigmoid
                Bc[j] = kkv * sg;
            }

            // sa = -(S_old . kk)
            float s01 = fmaf(S[1], Ac[1], S[0] * Ac[0]);
            float s23 = fmaf(S[3], Ac[3], S[2] * Ac[2]);
            const float sa = -bfly16(s01 + s23);

            // S = S*dec + sa*bb + v*k ;  y partial = S_new . r
            float t0 = fmaf(sa, Bc[0], vcv * Kc[0]);
            S[0] = fmaf(S[0], Dc[0], t0);
            float t1 = fmaf(sa, Bc[1], vcv * Kc[1]);
            S[1] = fmaf(S[1], Dc[1], t1);
            float y01 = fmaf(S[1], Rc[1], S[0] * Rc[0]);
            float t2 = fmaf(sa, Bc[2], vcv * Kc[2]);
            S[2] = fmaf(S[2], Dc[2], t2);
            float t3 = fmaf(sa, Bc[3], vcv * Kc[3]);
            S[3] = fmaf(S[3], Dc[3], t3);
            float y23 = fmaf(S[3], Rc[3], S[2] * Rc[2]);
            float ys = bfly16(y01 + y23);
            if (jg == 0)
                y[((size_t)b * T_ + t) * D_ + h * 64 + row] = __float2bfloat16(ys);
        }

        asm volatile("s_barrier" ::: "memory");   // all done reading slot g&1

        if (wave == 0) {
            // refill slot g&1 with group g+2 (clamped tail re-reads: harmless)
            int gp = g + 2; if (gp > T_ / 4 - 1) gp = T_ / 4 - 1;
            float* l0 = &ring[(g & 1) * 1280];
#pragma unroll
            for (int i = 0; i < 4; ++i) {
                size_t base = ((size_t)(b * T_ + gp * 4 + i) * H_ + h) * 64 + lane;
                float* l = l0 + i * 320;
                gld4(r + base, l);
                gld4(w + base, l + 64);
                gld4(k + base, l + 128);
                gld4(v + base, l + 192);
                gld4(iclr + base, l + 256);
            }
        }
    }
}

// ---------------------------------------------------------------------------
// Kernel 2: C[m,o] = scale[o] * sum_d Y[m,d] * Wq[o,d]  (B^T GEMM)
// R7: 128x128 tile (2x arithmetic intensity per ds_read vs 128x64), BK=64,
// 4 waves (2x2 over 64x64 sub-tiles), 2-phase counted-vmcnt prefetch
// (double-buffered 64KB LDS; stage t+1 issued BEFORE vmcnt(8)+barrier for
// tile t -- DMAs stay in flight across barriers, no drain). Grid 256 = 8
// XCD x 32, bijective swizzle for B-panel L2 locality.
// Per-wave ledger: GSTAGE = 8 DMAs/wave. After issuing stage t+1:
// queue = [8 t][8 t+1] -> vmcnt(8); last tile vmcnt(0).
// ---------------------------------------------------------------------------
__device__ __forceinline__ void gload_lds16(const __hip_bfloat16* g, ushort* l) {
    __builtin_amdgcn_global_load_lds(
        (const __attribute__((address_space(1))) unsigned int*)g,
        (__attribute__((address_space(3))) unsigned int*)l, 16, 0, 0);
}

__global__ __launch_bounds__(256) void gemm_bt(
    const __hip_bfloat16* __restrict__ A,   // [M, K]
    const __hip_bfloat16* __restrict__ Bq,  // [N, K]
    const float* __restrict__ scale,        // [N]
    float* __restrict__ C) {                // [M, N]
    const int K = D_;
    __shared__ __align__(16) ushort As[2][128 * 64];   // 32 KB
    __shared__ __align__(16) ushort Bs[2][128 * 64];   // 32 KB

    const int tid = threadIdx.x;
    const int lane = tid & 63;
    const int wave = tid >> 6;
    const int wr = wave >> 1, wc = wave & 1;

    // XCD-bijective swizzle: 256 blocks = 8 XCDs x 32 chunks
    const int id = blockIdx.x;
    const int swz = (id & 7) * 32 + (id >> 3);
    const int m0 = (swz & 15) * 128;
    const int n0 = (swz >> 4) * 128;

    const int srow8 = lane >> 3;
    const int scol8 = (lane & 7) * 8;
    const int ml = lane & 15;
    const int kq = (lane >> 4) * 8;

    f32x4 acc[4][4] = {};

#define GSTAGE(slot, kk0)                                                    \
    {                                                                        \
        _Pragma("unroll")                                                    \
        for (int c = 0; c < 4; ++c) {                                        \
            int ra = wave * 32 + c * 8;                                      \
            gload_lds16(A + (size_t)(m0 + ra + srow8) * K + (kk0) + scol8,   \
                        &As[slot][ra * 64]);                                 \
            gload_lds16(Bq + (size_t)(n0 + ra + srow8) * K + (kk0) + scol8,  \
                        &Bs[slot][ra * 64]);                                 \
        }                                                                    \
    }

    GSTAGE(0, 0);                         // prologue: stage tile 0

    for (int t = 0; t < K / 64; ++t) {
        if (t + 1 < K / 64) {
            GSTAGE((t + 1) & 1, (t + 1) * 64);   // issue next tile's DMAs
            asm volatile("s_waitcnt vmcnt(8)" ::: "memory");  // tile t landed
        } else {
            asm volatile("s_waitcnt vmcnt(0)" ::: "memory");
        }
        asm volatile("s_barrier" ::: "memory");
        const int sl = t & 1;
#pragma unroll
        for (int ks = 0; ks < 2; ++ks) {
            short8 af[4], bf[4];
#pragma unroll
            for (int tm = 0; tm < 4; ++tm)
                af[tm] = *(const short8*)(&As[sl][(wr * 64 + tm * 16 + ml) * 64 + ks * 32 + kq]);
#pragma unroll
            for (int tn = 0; tn < 4; ++tn)
                bf[tn] = *(const short8*)(&Bs[sl][(wc * 64 + tn * 16 + ml) * 64 + ks * 32 + kq]);
#pragma unroll
            for (int tm = 0; tm < 4; ++tm)
#pragma unroll
                for (int tn = 0; tn < 4; ++tn)
                    acc[tm][tn] = __builtin_amdgcn_mfma_f32_16x16x32_bf16(
                        af[tm], bf[tn], acc[tm][tn], 0, 0, 0);
        }
        asm volatile("s_barrier" ::: "memory");   // done reading slot sl
    }
#undef GSTAGE

#pragma unroll
    for (int tn = 0; tn < 4; ++tn) {
        int gn = n0 + wc * 64 + tn * 16 + ml;
        float sc = scale[gn];
#pragma unroll
        for (int tm = 0; tm < 4; ++tm) {
            int gm = m0 + wr * 64 + tm * 16 + (lane >> 4) * 4;
#pragma unroll
            for (int rg = 0; rg < 4; ++rg)
                C[(size_t)(gm + rg) * D_ + gn] = acc[tm][tn][rg] * sc;
        }
    }
}

// ---------------------------------------------------------------------------
extern "C" void kernel_launch(void* const* d_in, const int* in_sizes, int n_in,
                              void* d_out, int out_size, void* d_ws, size_t ws_size,
                              hipStream_t stream) {
    (void)in_sizes; (void)n_in; (void)out_size; (void)ws_size;
    const float* r  = (const float*)d_in[0];
    const float* w  = (const float*)d_in[1];
    const float* k  = (const float*)d_in[2];
    const float* v  = (const float*)d_in[3];
    const float* ic = (const float*)d_in[4];
    const int*   wq = (const int*)d_in[5];
    const float* sc = (const float*)d_in[6];
    float* out = (float*)d_out;

    // ws: yb 8.4MB | wb 8.4MB  (pk deleted -- prep fused into wkv_scan)
    char* p = (char*)d_ws;
    __hip_bfloat16* yb = (__hip_bfloat16*)p;  p += (size_t)M_ * D_ * 2;
    __hip_bfloat16* wb = (__hip_bfloat16*)p;

    wkv_scan<<<dim3(256 + 2048), dim3(512), 0, stream>>>(r, w, k, v, ic, yb, wq, wb);
    gemm_bt <<<dim3(256), dim3(256), 0, stream>>>(yb, wb, sc, out);
}

// Round 8
// 289.711 us; speedup vs baseline: 1.3449x; 1.3449x over previous
//
#include <hip/hip_runtime.h>
#include <hip/hip_bf16.h>
#include <stdint.h>

#define B_ 4
#define T_ 512
#define H_ 32
#define N_ 64
#define D_ 2048
#define M_ (B_*T_)

typedef __attribute__((ext_vector_type(4))) float f32x4;
typedef __attribute__((ext_vector_type(8))) short short8;

// DPP butterfly add across 16-lane groups: pure VALU.
template <int CTRL>
__device__ __forceinline__ float dpp_add(float x) {
    int t = __builtin_amdgcn_mov_dpp(__float_as_int(x), CTRL, 0xF, 0xF, true);
    return x + __int_as_float(t);
}
__device__ __forceinline__ float bfly16(float x) {
    x = dpp_add<0xB1>(x);    // xor1
    x = dpp_add<0x4E>(x);    // xor2
    x = dpp_add<0x141>(x);   // xor4 row_half_mirror
    x = dpp_add<0x140>(x);   // xor8 row_mirror
    return x;
}

__device__ __forceinline__ void gld16(const float* g, float* l) {
    __builtin_amdgcn_global_load_lds(
        (const __attribute__((address_space(1))) unsigned int*)g,
        (__attribute__((address_space(3))) unsigned int*)l, 16, 0, 0);
}

// ---------------------------------------------------------------------------
// Kernel 1: precompute+pack streams into pk[bh][t][6][64] f32
// (streams: r,k,v,dec,kk,bb) -- R6 version verbatim (proven).
// R7 lesson: fusing this into the scan makes all 16 sibling waves repeat
// the same TRANS-pipe work (VALUBusy 38->62%, wkv 124->258us). Keep split.
// ---------------------------------------------------------------------------
__global__ __launch_bounds__(256) void prep(
    const float* __restrict__ r, const float* __restrict__ w,
    const float* __restrict__ k, const float* __restrict__ v,
    const float* __restrict__ iclr, float* __restrict__ pk) {
    int g = blockIdx.x * 4 + (threadIdx.x >> 6);   // (b,t,h) flat index
    int lane = threadIdx.x & 63;
    int b = g >> 14;             // / (T*H)
    int t = (g >> 5) & (T_ - 1); // / H % T
    int h = g & 31;              // % H
    size_t si = (size_t)g * 64 + lane;
    size_t di = (((size_t)(b * H_ + h) * T_) + t) * 384 + lane;  // stream 0 chan
    float rv = r[si], wv = w[si], kv = k[si], vv = v[si], av = iclr[si];
    float d = expf(-expf(wv));
    float ss = kv * kv;
#pragma unroll
    for (int m = 1; m < 64; m <<= 1) ss += __shfl_xor(ss, m, 64);
    float kkv = kv * rsqrtf(ss + 1e-12f);
    float bbv = kkv * (1.f / (1.f + expf(-av)));
    pk[di          ] = rv;
    pk[di + 1 * 64 ] = kv;
    pk[di + 2 * 64 ] = vv;
    pk[di + 3 * 64 ] = d;
    pk[di + 4 * 64 ] = kkv;
    pk[di + 5 * 64 ] = bbv;
}

// ---------------------------------------------------------------------------
// Kernel 2: WKV-7 scan, sibling-merged -- R6 version verbatim (124us proven).
// ONE 512-thread block (8 waves) per (bh, half); ONE shared ring; wave 0 is
// the sole DMA producer. Sync = raw s_barrier pairs + producer counted vmcnt.
// wave0 vmcnt ledger: top of group g, queue = [6 DMA g][4 st g-1]
// [6 DMA g+1] -> vmcnt(10) retires exactly data-g. g==0: vmcnt(6).
// Blocks >= 256: int32 -> bf16 weight dequant riding in the scan's shadow.
// ---------------------------------------------------------------------------
__global__ __launch_bounds__(512) void wkv_scan(
    const float* __restrict__ pk, __hip_bfloat16* __restrict__ y,
    const int* __restrict__ q, __hip_bfloat16* __restrict__ o) {
    if (blockIdx.x >= 256) {       // ---- weight dequant part ----
        int i = ((blockIdx.x - 256) * 512 + (int)threadIdx.x) * 4;
        int4 qi = *(const int4*)(q + i);
        __hip_bfloat16 t[4];
        t[0] = __float2bfloat16((float)qi.x);
        t[1] = __float2bfloat16((float)qi.y);
        t[2] = __float2bfloat16((float)qi.z);
        t[3] = __float2bfloat16((float)qi.w);
        *(uint2*)(o + i) = *(uint2*)t;
        return;
    }
    const int bh   = blockIdx.x & 127;
    const int half = blockIdx.x >> 7;
    const int tid  = threadIdx.x;
    const int wave = tid >> 6;
    const int lane = tid & 63;
    const int b = bh >> 5, h = bh & 31;
    const int jg = lane & 15;
    const int rl = lane >> 4;
    const int row = (half * 8 + wave) * 4 + rl;

    __shared__ __align__(16) float ring[2 * 1536];   // 12 KB, shared by 8 waves

    const float* src = pk + (size_t)bh * T_ * 384;

    // prologue: producer fills both superslots (12 DMAs outstanding)
    if (wave == 0) {
#pragma unroll
        for (int gg = 0; gg < 2; ++gg)
#pragma unroll
            for (int c = 0; c < 6; ++c)
                gld16(src + gg * 1536 + c * 256 + lane * 4,
                      &ring[gg * 1536 + c * 256]);
    }

    float S[4] = {0.f, 0.f, 0.f, 0.f};

    for (int g = 0; g < T_ / 4; ++g) {
        if (wave == 0) {
            if (g == 0) { asm volatile("s_waitcnt vmcnt(6)"  ::: "memory"); }
            else        { asm volatile("s_waitcnt vmcnt(10)" ::: "memory"); }
        }
        asm volatile("s_barrier" ::: "memory");   // slot g&1 holds data g
        const float* rb0 = &ring[(g & 1) * 1536];

#pragma unroll
        for (int i = 0; i < 4; ++i) {
            const int t = g * 4 + i;
            const float* rb = rb0 + i * 384;

            f32x4 Rc = *(const f32x4*)(rb + 0 * 64 + jg * 4);
            f32x4 Kc = *(const f32x4*)(rb + 1 * 64 + jg * 4);
            float vcv =                 rb[2 * 64 + row];
            f32x4 Dc = *(const f32x4*)(rb + 3 * 64 + jg * 4);
            f32x4 Ac = *(const f32x4*)(rb + 4 * 64 + jg * 4);
            f32x4 Bc = *(const f32x4*)(rb + 5 * 64 + jg * 4);

            // sa = -(S_old . kk)
            float s01 = fmaf(S[1], Ac[1], S[0] * Ac[0]);
            float s23 = fmaf(S[3], Ac[3], S[2] * Ac[2]);
            const float sa = -bfly16(s01 + s23);

            // S = S*dec + sa*bb + v*k ;  y partial = S_new . r
            float t0 = fmaf(sa, Bc[0], vcv * Kc[0]);
            S[0] = fmaf(S[0], Dc[0], t0);
            float t1 = fmaf(sa, Bc[1], vcv * Kc[1]);
            S[1] = fmaf(S[1], Dc[1], t1);
            float y01 = fmaf(S[1], Rc[1], S[0] * Rc[0]);
            float t2 = fmaf(sa, Bc[2], vcv * Kc[2]);
            S[2] = fmaf(S[2], Dc[2], t2);
            float t3 = fmaf(sa, Bc[3], vcv * Kc[3]);
            S[3] = fmaf(S[3], Dc[3], t3);
            float y23 = fmaf(S[3], Rc[3], S[2] * Rc[2]);
            float ys = bfly16(y01 + y23);
            if (jg == 0)
                y[((size_t)b * T_ + t) * D_ + h * 64 + row] = __float2bfloat16(ys);
        }

        asm volatile("s_barrier" ::: "memory");   // all done reading slot g&1

        if (wave == 0) {
            // refill slot g&1 with group g+2 (clamped tail re-reads: harmless)
            int gp = g + 2; if (gp > T_ / 4 - 1) gp = T_ / 4 - 1;
            const float* g0 = src + (size_t)gp * 1536 + lane * 4;
            float* l0 = &ring[(g & 1) * 1536];
#pragma unroll
            for (int c = 0; c < 6; ++c)
                gld16(g0 + c * 256, l0 + c * 256);
        }
    }
}

// ---------------------------------------------------------------------------
// Kernel 3: C[m,o] = scale[o] * sum_d Y[m,d] * Wq[o,d]  (B^T GEMM)
// R8: gemm identified as ~120us (145 TF) by subtraction across R5-R7 --
// the dominant hidden cost. Root cause: linear [128][64]-ushort LDS tiles
// are the known 16-way ds_read_b128 bank conflict (row stride 128B; only
// 16 banks used -> ~16cyc/b128; LDS-read-bound at ~1280 cyc/tile/CU vs
// MFMA 620). Fix = T2 XOR swizzle, both-sides-or-neither (rule #21):
//   - DMA dest stays linear (gload_lds requirement)
//   - global SOURCE col pre-swizzled: elem ((l&7)^(l>>3))*8
//   - ds_read index swizzled:  elem ((ks*4+q)^(ml&7))*8,  q=lane>>4
// giving LDS[row][col ^ ((row&7)<<4 bytes)] = A[row][col] -> all 32 banks,
// ~2-way residual (free). Keep 128x128, counted-vmcnt 2-phase (stage t+1
// issued BEFORE vmcnt(8)+barrier for tile t), XCD-bijective swizzle.
// ---------------------------------------------------------------------------
__device__ __forceinline__ void gload_lds16(const __hip_bfloat16* g, ushort* l) {
    __builtin_amdgcn_global_load_lds(
        (const __attribute__((address_space(1))) unsigned int*)g,
        (__attribute__((address_space(3))) unsigned int*)l, 16, 0, 0);
}

__global__ __launch_bounds__(256, 1) void gemm_bt(
    const __hip_bfloat16* __restrict__ A,   // [M, K]
    const __hip_bfloat16* __restrict__ Bq,  // [N, K]
    const float* __restrict__ scale,        // [N]
    float* __restrict__ C) {                // [M, N]
    const int K = D_;
    __shared__ __align__(16) ushort As[2][128 * 64];   // 32 KB
    __shared__ __align__(16) ushort Bs[2][128 * 64];   // 32 KB

    const int tid = threadIdx.x;
    const int lane = tid & 63;
    const int wave = tid >> 6;
    const int wr = wave >> 1, wc = wave & 1;

    // XCD-bijective swizzle: 256 blocks = 8 XCDs x 32 chunks; each XCD owns
    // 2 n-strips (1MB of B L2-resident) x all 16 m-tiles.
    const int id = blockIdx.x;
    const int swz = (id & 7) * 32 + (id >> 3);
    const int m0 = (swz & 15) * 128;
    const int n0 = (swz >> 4) * 128;

    const int srow8 = lane >> 3;
    const int scolS = (((lane & 7) ^ (lane >> 3)) * 8);  // pre-swizzled src col
    const int ml = lane & 15;
    const int q4 = lane >> 4;
    const int m7 = ml & 7;

    f32x4 acc[4][4] = {};

#define GSTAGE(slot, kk0)                                                    \
    {                                                                        \
        _Pragma("unroll")                                                    \
        for (int c = 0; c < 4; ++c) {                                        \
            int ra = wave * 32 + c * 8;                                      \
            gload_lds16(A + (size_t)(m0 + ra + srow8) * K + (kk0) + scolS,   \
                        &As[slot][ra * 64]);                                 \
            gload_lds16(Bq + (size_t)(n0 + ra + srow8) * K + (kk0) + scolS,  \
                        &Bs[slot][ra * 64]);                                 \
        }                                                                    \
    }

    GSTAGE(0, 0);                         // prologue: stage tile 0

    for (int t = 0; t < K / 64; ++t) {
        if (t + 1 < K / 64) {
            GSTAGE((t + 1) & 1, (t + 1) * 64);   // issue next tile's DMAs
            asm volatile("s_waitcnt vmcnt(8)" ::: "memory");  // tile t landed
        } else {
            asm volatile("s_waitcnt vmcnt(0)" ::: "memory");
        }
        asm volatile("s_barrier" ::: "memory");
        const int sl = t & 1;
#pragma unroll
        for (int ks = 0; ks < 2; ++ks) {
            const int blk = ((ks * 4 + q4) ^ m7) * 8;   // swizzled read col
            short8 af[4], bf[4];
#pragma unroll
            for (int tm = 0; tm < 4; ++tm)
                af[tm] = *(const short8*)(&As[sl][(wr * 64 + tm * 16 + ml) * 64 + blk]);
#pragma unroll
            for (int tn = 0; tn < 4; ++tn)
                bf[tn] = *(const short8*)(&Bs[sl][(wc * 64 + tn * 16 + ml) * 64 + blk]);
#pragma unroll
            for (int tm = 0; tm < 4; ++tm)
#pragma unroll
                for (int tn = 0; tn < 4; ++tn)
                    acc[tm][tn] = __builtin_amdgcn_mfma_f32_16x16x32_bf16(
                        af[tm], bf[tn], acc[tm][tn], 0, 0, 0);
        }
        asm volatile("s_barrier" ::: "memory");   // done reading slot sl
    }
#undef GSTAGE

#pragma unroll
    for (int tn = 0; tn < 4; ++tn) {
        int gn = n0 + wc * 64 + tn * 16 + ml;
        float sc = scale[gn];
#pragma unroll
        for (int tm = 0; tm < 4; ++tm) {
            int gm = m0 + wr * 64 + tm * 16 + (lane >> 4) * 4;
#pragma unroll
            for (int rg = 0; rg < 4; ++rg)
                C[(size_t)(gm + rg) * D_ + gn] = acc[tm][tn][rg] * sc;
        }
    }
}

// ---------------------------------------------------------------------------
extern "C" void kernel_launch(void* const* d_in, const int* in_sizes, int n_in,
                              void* d_out, int out_size, void* d_ws, size_t ws_size,
                              hipStream_t stream) {
    (void)in_sizes; (void)n_in; (void)out_size; (void)ws_size;
    const float* r  = (const float*)d_in[0];
    const float* w  = (const float*)d_in[1];
    const float* k  = (const float*)d_in[2];
    const float* v  = (const float*)d_in[3];
    const float* ic = (const float*)d_in[4];
    const int*   wq = (const int*)d_in[5];
    const float* sc = (const float*)d_in[6];
    float* out = (float*)d_out;

    // ws: yb 8.4MB | wb 8.4MB | pk (packed streams) 100.7MB  (~118 MB total)
    char* p = (char*)d_ws;
    __hip_bfloat16* yb = (__hip_bfloat16*)p;  p += (size_t)M_ * D_ * 2;
    __hip_bfloat16* wb = (__hip_bfloat16*)p;  p += (size_t)D_ * D_ * 2;
    float* pk = (float*)p;

    prep    <<<dim3(16384), dim3(256), 0, stream>>>(r, w, k, v, ic, pk);
    wkv_scan<<<dim3(256 + 2048), dim3(512), 0, stream>>>(pk, yb, wq, wb);
    gemm_bt <<<dim3(256), dim3(256), 0, stream>>>(yb, wb, sc, out);
}